// Round 1
// baseline (354.523 us; speedup 1.0000x reference)
//
#include <hip/hip_runtime.h>
#include <hip/hip_bf16.h>

// S5 layer on MI355X.
// Decomposition:
//   v[b,t,:] = Mv (128x512) @ u[b,t,:]            (GEMM1)
//   x[t] = A*x[t-1] + v[t]   complex, 64 poles     (3-phase chunked scan)
//   y[b,t,:] = Wx (512x128) @ [xr;xi] + D @ u      (GEMM2 + GEMM3)
// All fp32 this round; MFMA bf16 in later rounds.

#define BATCH 8
#define SEQ   4096
#define DMODEL 512
#define HALF  64
#define CHUNK 64
#define NCHUNK (SEQ / CHUNK)   // 64

// ---------------- precompute kernels ----------------

// 64 threads: per-pole constants. A = (1 + d/2*L)/(1 - d/2*L), s = d/denom,
// plus power table Apow[k][n] = A^k for k=0..64.
__global__ void k_consts(const float* __restrict__ logLr,
                         const float* __restrict__ Li_in,
                         const float* __restrict__ logDelta,
                         float* __restrict__ sr, float* __restrict__ si,
                         float* __restrict__ ApR, float* __restrict__ ApI) {
    int n = threadIdx.x;  // 0..63
    float Delta = expf(logDelta[0]);
    float llr = logLr[n];
    llr = fminf(fmaxf(llr, -10.f), 10.f);
    float Lr = -expf(llr);
    float Li = Li_in[n];
    float dr = 1.f - 0.5f * Delta * Lr;
    float di = -0.5f * Delta * Li;
    float dn = dr * dr + di * di;
    float nr = 1.f + 0.5f * Delta * Lr;
    float ni = 0.5f * Delta * Li;
    float Ar = (nr * dr + ni * di) / dn;
    float Ai = (ni * dr - nr * di) / dn;
    sr[n] = Delta * dr / dn;
    si[n] = -Delta * di / dn;
    float pr = 1.f, pi = 0.f;
    for (int k = 0; k <= CHUNK; ++k) {
        ApR[k * HALF + n] = pr;
        ApI[k * HALF + n] = pi;
        float npr = pr * Ar - pi * Ai;
        float npi = pr * Ai + pi * Ar;
        pr = npr; pi = npi;
    }
}

// Mv: 128x512. rows 0..63 real part of B_bar, rows 64..127 imag part.
__global__ void k_build_Mv(const float* __restrict__ Br, const float* __restrict__ Bi,
                           const float* __restrict__ sr, const float* __restrict__ si,
                           float* __restrict__ Mv) {
    int idx = blockIdx.x * 256 + threadIdx.x;  // 65536
    int p = idx & 511;
    int np = idx >> 9;  // 0..127
    int n = np & 63;
    float br = Br[n * DMODEL + p], bi = Bi[n * DMODEL + p];
    float v = (np < HALF) ? (sr[n] * br - si[n] * bi)
                          : (si[n] * br + sr[n] * bi);
    Mv[idx] = v;
}

// Wx: 512x128. Wx[p][j] = j<64 ? 2*Cr[p][j] : -2*Ci[p][j-64]
__global__ void k_build_Wx(const float* __restrict__ Cr, const float* __restrict__ Ci,
                           float* __restrict__ Wx) {
    int idx = blockIdx.x * 256 + threadIdx.x;  // 65536
    int j = idx & 127;
    int p = idx >> 7;
    float v = (j < HALF) ? 2.f * Cr[p * HALF + j] : -2.f * Ci[p * HALF + (j - HALF)];
    Wx[idx] = v;
}

// ---------------- scan kernels ----------------

// Phase A: per-(b,chunk,n) local scan, in place on V; store chunk-end states E.
__global__ void k_scanA(float* __restrict__ V,
                        const float* __restrict__ ApR, const float* __restrict__ ApI,
                        float* __restrict__ E) {
    int tid = threadIdx.x;
    int n = tid & 63;
    int cc = tid >> 6;                      // 0..3
    int b = blockIdx.x >> 4;                // NCHUNK/4 = 16 blocks per batch
    int c = ((blockIdx.x & 15) << 2) + cc;  // chunk 0..63
    float Ar = ApR[HALF + n], Ai = ApI[HALF + n];  // A^1
    float xr = 0.f, xi = 0.f;
    size_t base = ((size_t)b * SEQ + (size_t)c * CHUNK) * 128 + n;
    for (int tl = 0; tl < CHUNK; ++tl) {
        float vr = V[base], vi = V[base + 64];
        float nxr = Ar * xr - Ai * xi + vr;
        float nxi = Ar * xi + Ai * xr + vi;
        xr = nxr; xi = nxi;
        V[base] = xr; V[base + 64] = xi;
        base += 128;
    }
    int eidx = ((b * NCHUNK + c) * 2) * HALF + n;
    E[eidx] = xr; E[eidx + 64] = xi;
}

// Phase B: serial carry prefix over chunks. 8 blocks x 64 threads.
__global__ void k_scanB(const float* __restrict__ E, float* __restrict__ Carry,
                        const float* __restrict__ ApR, const float* __restrict__ ApI) {
    int n = threadIdx.x;  // 0..63
    int b = blockIdx.x;   // 0..7
    float ALr = ApR[CHUNK * HALF + n], ALi = ApI[CHUNK * HALF + n];  // A^64
    float Gr = 0.f, Gi = 0.f;
    for (int c = 0; c < NCHUNK; ++c) {
        int idx = ((b * NCHUNK + c) * 2) * HALF + n;
        Carry[idx] = Gr; Carry[idx + 64] = Gi;
        float er = E[idx], ei = E[idx + 64];
        float ngr = ALr * Gr - ALi * Gi + er;
        float ngi = ALr * Gi + ALi * Gr + ei;
        Gr = ngr; Gi = ngi;
    }
}

// Phase C: x_global[t] = local[t] + A^(tl+1) * carry[chunk]
__global__ void k_scanC(float* __restrict__ V, const float* __restrict__ Carry,
                        const float* __restrict__ ApR, const float* __restrict__ ApI) {
    int tid = threadIdx.x;
    int n = tid & 63;
    int cc = tid >> 6;
    int b = blockIdx.x >> 4;
    int c = ((blockIdx.x & 15) << 2) + cc;
    if (c == 0) return;  // zero carry
    int cidx = ((b * NCHUNK + c) * 2) * HALF + n;
    float cr = Carry[cidx], ci = Carry[cidx + 64];
    size_t base = ((size_t)b * SEQ + (size_t)c * CHUNK) * 128 + n;
    for (int tl = 0; tl < CHUNK; ++tl) {
        float pr = ApR[(tl + 1) * HALF + n], pi = ApI[(tl + 1) * HALF + n];
        V[base]      += pr * cr - pi * ci;
        V[base + 64] += pr * ci + pi * cr;
        base += 128;
    }
}

// ---------------- generic fp32 GEMM, C[m][n] = sum_k A[m][k]*B[n][k] ----------------
// 128x128 tile, BK=16, 256 threads, 8x8 per thread.
template <int BETA>
__global__ __launch_bounds__(256) void sgemm_bt(const float* __restrict__ A,
                                                const float* __restrict__ B,
                                                float* __restrict__ C,
                                                int M, int N, int K) {
    __shared__ float As[16][128];
    __shared__ float Bs[16][128];
    const int tid = threadIdx.x;
    const int tx = tid & 15, ty = tid >> 4;
    const int row0 = blockIdx.x * 128;
    const int col0 = blockIdx.y * 128;
    float acc[8][8];
#pragma unroll
    for (int i = 0; i < 8; ++i)
#pragma unroll
        for (int j = 0; j < 8; ++j) acc[i][j] = 0.f;

    for (int k0 = 0; k0 < K; k0 += 16) {
#pragma unroll
        for (int i = 0; i < 2; ++i) {
            int f = tid * 2 + i;         // 0..511
            int r = f >> 2;              // 0..127
            int kq = (f & 3) << 2;       // 0,4,8,12
            const float4 av = *(const float4*)(A + (size_t)(row0 + r) * K + k0 + kq);
            As[kq + 0][r] = av.x; As[kq + 1][r] = av.y;
            As[kq + 2][r] = av.z; As[kq + 3][r] = av.w;
            const float4 bv = *(const float4*)(B + (size_t)(col0 + r) * K + k0 + kq);
            Bs[kq + 0][r] = bv.x; Bs[kq + 1][r] = bv.y;
            Bs[kq + 2][r] = bv.z; Bs[kq + 3][r] = bv.w;
        }
        __syncthreads();
#pragma unroll
        for (int k = 0; k < 16; ++k) {
            float a[8], b[8];
            *(float4*)&a[0] = *(const float4*)&As[k][ty * 8];
            *(float4*)&a[4] = *(const float4*)&As[k][ty * 8 + 4];
            *(float4*)&b[0] = *(const float4*)&Bs[k][tx * 8];
            *(float4*)&b[4] = *(const float4*)&Bs[k][tx * 8 + 4];
#pragma unroll
            for (int i = 0; i < 8; ++i)
#pragma unroll
                for (int j = 0; j < 8; ++j) acc[i][j] += a[i] * b[j];
        }
        __syncthreads();
    }
#pragma unroll
    for (int i = 0; i < 8; ++i) {
        int row = row0 + ty * 8 + i;
#pragma unroll
        for (int j = 0; j < 8; j += 4) {
            float4* cp = (float4*)(C + (size_t)row * N + col0 + tx * 8 + j);
            float4 v = make_float4(acc[i][j], acc[i][j + 1], acc[i][j + 2], acc[i][j + 3]);
            if (BETA) {
                float4 o = *cp;
                v.x += o.x; v.y += o.y; v.z += o.z; v.w += o.w;
            }
            *cp = v;
        }
    }
}

// ---------------- launch ----------------

extern "C" void kernel_launch(void* const* d_in, const int* in_sizes, int n_in,
                              void* d_out, int out_size, void* d_ws, size_t ws_size,
                              hipStream_t stream) {
    const float* u      = (const float*)d_in[0];
    const float* logLr  = (const float*)d_in[1];
    const float* Li     = (const float*)d_in[2];
    const float* Br     = (const float*)d_in[3];
    const float* Bi     = (const float*)d_in[4];
    const float* Cr     = (const float*)d_in[5];
    const float* Ci     = (const float*)d_in[6];
    const float* D      = (const float*)d_in[7];
    const float* logDel = (const float*)d_in[8];
    float* out = (float*)d_out;

    float* ws = (float*)d_ws;
    const size_t M = (size_t)BATCH * SEQ;  // 32768
    float* V     = ws;                       // M*128 = 4,194,304
    float* Mv    = V + M * 128;              // 65536
    float* Wx    = Mv + 65536;               // 65536
    float* E     = Wx + 65536;               // 65536
    float* Carry = E + 65536;                // 65536
    float* ApR   = Carry + 65536;            // 65*64
    float* ApI   = ApR + 65 * 64;
    float* sr    = ApI + 65 * 64;
    float* si    = sr + 64;

    hipLaunchKernelGGL(k_consts, dim3(1), dim3(64), 0, stream,
                       logLr, Li, logDel, sr, si, ApR, ApI);
    hipLaunchKernelGGL(k_build_Mv, dim3(256), dim3(256), 0, stream, Br, Bi, sr, si, Mv);
    hipLaunchKernelGGL(k_build_Wx, dim3(256), dim3(256), 0, stream, Cr, Ci, Wx);

    // GEMM1: V = U (32768x512) * Mv^T (128x512)
    hipLaunchKernelGGL((sgemm_bt<0>), dim3(M / 128, 1), dim3(256), 0, stream,
                       u, Mv, V, (int)M, 128, DMODEL);

    // scan
    hipLaunchKernelGGL(k_scanA, dim3(BATCH * (NCHUNK / 4)), dim3(256), 0, stream, V, ApR, ApI, E);
    hipLaunchKernelGGL(k_scanB, dim3(BATCH), dim3(64), 0, stream, E, Carry, ApR, ApI);
    hipLaunchKernelGGL(k_scanC, dim3(BATCH * (NCHUNK / 4)), dim3(256), 0, stream, V, Carry, ApR, ApI);

    // GEMM2: out = X (32768x128) * Wx^T (512x128)
    hipLaunchKernelGGL((sgemm_bt<0>), dim3(M / 128, DMODEL / 128), dim3(256), 0, stream,
                       V, Wx, out, (int)M, DMODEL, 128);
    // GEMM3: out += U (32768x512) * D^T (512x512)
    hipLaunchKernelGGL((sgemm_bt<1>), dim3(M / 128, DMODEL / 128), dim3(256), 0, stream,
                       u, D, out, (int)M, DMODEL, DMODEL);
}

// Round 2
// 106.423 us; speedup vs baseline: 3.3312x; 3.3312x over previous
//
#include <hip/hip_runtime.h>
#include <hip/hip_bf16.h>
#include <stdint.h>

// S5 layer on MI355X — bf16 MFMA round.
//   V = U (fp32) @ Mv^T (bf16)                      GEMM1  (MFMA)
//   x[t] = A x[t-1] + v[t]  (complex, fp32, in-place in V)   3-phase scan
//   Y = [X | U] @ [2Cr | -2Ci | D]^T                GEMM23 fused (MFMA, K=640)

#define BATCH 8
#define SEQ   4096
#define DMODEL 512
#define HALF  64
#define CHUNK 64
#define NCHUNK (SEQ / CHUNK)   // 64

typedef __attribute__((ext_vector_type(8))) short short8;   // 8 bf16 (4 VGPRs)
typedef __attribute__((ext_vector_type(4))) float f32x4;

__device__ __forceinline__ unsigned short f2bf(float f) {
    unsigned int u = __float_as_uint(f);
    u += 0x7fffu + ((u >> 16) & 1u);   // round-to-nearest-even
    return (unsigned short)(u >> 16);
}

// ---------------- precompute ----------------

__global__ void k_consts(const float* __restrict__ logLr,
                         const float* __restrict__ Li_in,
                         const float* __restrict__ logDelta,
                         float* __restrict__ sr, float* __restrict__ si,
                         float* __restrict__ ApR, float* __restrict__ ApI) {
    int n = threadIdx.x;  // 0..63
    float Delta = expf(logDelta[0]);
    float llr = fminf(fmaxf(logLr[n], -10.f), 10.f);
    float Lr = -expf(llr);
    float Li = Li_in[n];
    float dr = 1.f - 0.5f * Delta * Lr;
    float di = -0.5f * Delta * Li;
    float dn = dr * dr + di * di;
    float nr = 1.f + 0.5f * Delta * Lr;
    float ni = 0.5f * Delta * Li;
    float Ar = (nr * dr + ni * di) / dn;
    float Ai = (ni * dr - nr * di) / dn;
    sr[n] = Delta * dr / dn;
    si[n] = -Delta * di / dn;
    float pr = 1.f, pi = 0.f;
    for (int k = 0; k <= CHUNK; ++k) {
        ApR[k * HALF + n] = pr;
        ApI[k * HALF + n] = pi;
        float npr = pr * Ar - pi * Ai;
        float npi = pr * Ai + pi * Ar;
        pr = npr; pi = npi;
    }
}

// Mv (bf16): 128x512. rows 0..63: Re(B_bar), rows 64..127: Im(B_bar).
// grid 128 (np), block 512 (p)
__global__ void k_build_Mv(const float* __restrict__ Br, const float* __restrict__ Bi,
                           const float* __restrict__ sr, const float* __restrict__ si,
                           unsigned short* __restrict__ Mv) {
    int np = blockIdx.x, p = threadIdx.x;
    int n = np & 63;
    float br = Br[n * DMODEL + p], bi = Bi[n * DMODEL + p];
    float v = (np < HALF) ? (sr[n] * br - si[n] * bi)
                          : (si[n] * br + sr[n] * bi);
    Mv[np * DMODEL + p] = f2bf(v);
}

// W (bf16): 512x640. W[p][j] = j<64 ? 2Cr[p][j] : j<128 ? -2Ci[p][j-64] : D[p][j-128]
// grid 512 (p), block 640 (j)
__global__ void k_build_W(const float* __restrict__ Cr, const float* __restrict__ Ci,
                          const float* __restrict__ D, unsigned short* __restrict__ W) {
    int p = blockIdx.x, j = threadIdx.x;
    float v;
    if (j < HALF) v = 2.f * Cr[p * HALF + j];
    else if (j < 2 * HALF) v = -2.f * Ci[p * HALF + (j - HALF)];
    else v = D[p * DMODEL + (j - 2 * HALF)];
    W[p * 640 + j] = f2bf(v);
}

// ---------------- scan (fp32, in place in V) ----------------

__global__ void k_scanA(float* __restrict__ V,
                        const float* __restrict__ ApR, const float* __restrict__ ApI,
                        float* __restrict__ E) {
    int tid = threadIdx.x;
    int n = tid & 63;
    int cc = tid >> 6;
    int b = blockIdx.x >> 4;
    int c = ((blockIdx.x & 15) << 2) + cc;
    float Ar = ApR[HALF + n], Ai = ApI[HALF + n];
    float xr = 0.f, xi = 0.f;
    size_t base = ((size_t)b * SEQ + (size_t)c * CHUNK) * 128 + n;
    for (int tl = 0; tl < CHUNK; ++tl) {
        float vr = V[base], vi = V[base + 64];
        float nxr = Ar * xr - Ai * xi + vr;
        float nxi = Ar * xi + Ai * xr + vi;
        xr = nxr; xi = nxi;
        V[base] = xr; V[base + 64] = xi;
        base += 128;
    }
    int eidx = ((b * NCHUNK + c) * 2) * HALF + n;
    E[eidx] = xr; E[eidx + 64] = xi;
}

__global__ void k_scanB(const float* __restrict__ E, float* __restrict__ Carry,
                        const float* __restrict__ ApR, const float* __restrict__ ApI) {
    int n = threadIdx.x;
    int b = blockIdx.x;
    float ALr = ApR[CHUNK * HALF + n], ALi = ApI[CHUNK * HALF + n];
    float Gr = 0.f, Gi = 0.f;
    for (int c = 0; c < NCHUNK; ++c) {
        int idx = ((b * NCHUNK + c) * 2) * HALF + n;
        Carry[idx] = Gr; Carry[idx + 64] = Gi;
        float er = E[idx], ei = E[idx + 64];
        float ngr = ALr * Gr - ALi * Gi + er;
        float ngi = ALr * Gi + ALi * Gr + ei;
        Gr = ngr; Gi = ngi;
    }
}

__global__ void k_scanC(float* __restrict__ V, const float* __restrict__ Carry,
                        const float* __restrict__ ApR, const float* __restrict__ ApI) {
    int tid = threadIdx.x;
    int n = tid & 63;
    int cc = tid >> 6;
    int b = blockIdx.x >> 4;
    int c = ((blockIdx.x & 15) << 2) + cc;
    if (c == 0) return;
    int cidx = ((b * NCHUNK + c) * 2) * HALF + n;
    float cr = Carry[cidx], ci = Carry[cidx + 64];
    size_t base = ((size_t)b * SEQ + (size_t)c * CHUNK) * 128 + n;
    for (int tl = 0; tl < CHUNK; ++tl) {
        float pr = ApR[(tl + 1) * HALF + n], pi = ApI[(tl + 1) * HALF + n];
        V[base]      += pr * cr - pi * ci;
        V[base + 64] += pr * ci + pi * cr;
        base += 128;
    }
}

// ---------------- MFMA GEMM: C[m][n] = sum_k A[m][k] * B[n][k] ----------------
// A fp32 (reg-staged -> bf16 cvt -> LDS), B bf16 (reg-staged -> LDS).
// 128x128 tile, BK=32, 256 threads = 4 waves (2x2), 16x16x32 bf16 MFMA, 4x4 frags/wave.
// SPLIT: A = A0 (lda0) for k < SPLIT, A = A1 (lda1, k-offset SPLIT) for k >= SPLIT.
template <int SPLIT>
__global__ __launch_bounds__(256) void mfma_gemm(
    const float* __restrict__ A0, int lda0,
    const float* __restrict__ A1, int lda1,
    const unsigned short* __restrict__ B, int ldb,
    float* __restrict__ C, int ldc, int K)
{
    __shared__ __align__(16) unsigned short As[128 * 32];
    __shared__ __align__(16) unsigned short Bs[128 * 32];
    const int tid = threadIdx.x;
    const int lane = tid & 63;
    const int w = tid >> 6;
    const int wm = w >> 1, wn = w & 1;
    const int l15 = lane & 15, l4 = lane >> 4;
    const int row0 = blockIdx.x * 128;
    const int col0 = blockIdx.y * 128;

    const int srow = tid >> 1;        // 0..127
    const int sh = (tid & 1) << 4;    // 0 or 16 (elements)

    f32x4 acc[4][4];
#pragma unroll
    for (int m = 0; m < 4; ++m)
#pragma unroll
        for (int n = 0; n < 4; ++n) acc[m][n] = (f32x4)(0.f);

    for (int k0 = 0; k0 < K; k0 += 32) {
        const float* ap; int lda, kk;
        if (SPLIT != 0 && k0 < SPLIT) { ap = A0; lda = lda0; kk = k0; }
        else { ap = A1; lda = lda1; kk = k0 - SPLIT; }

        // issue global loads early (latency hides under prior MFMA + barrier)
        const float* ag = ap + (size_t)(row0 + srow) * lda + kk + sh;
        float4 av0 = ((const float4*)ag)[0];
        float4 av1 = ((const float4*)ag)[1];
        float4 av2 = ((const float4*)ag)[2];
        float4 av3 = ((const float4*)ag)[3];
        const unsigned short* bg = B + (size_t)(col0 + srow) * ldb + k0 + sh;
        uint4 bv0 = ((const uint4*)bg)[0];
        uint4 bv1 = ((const uint4*)bg)[1];

        __syncthreads();   // prior iteration's LDS reads complete

        uint4 wa0, wa1;
        wa0.x = f2bf(av0.x) | ((unsigned)f2bf(av0.y) << 16);
        wa0.y = f2bf(av0.z) | ((unsigned)f2bf(av0.w) << 16);
        wa0.z = f2bf(av1.x) | ((unsigned)f2bf(av1.y) << 16);
        wa0.w = f2bf(av1.z) | ((unsigned)f2bf(av1.w) << 16);
        wa1.x = f2bf(av2.x) | ((unsigned)f2bf(av2.y) << 16);
        wa1.y = f2bf(av2.z) | ((unsigned)f2bf(av2.w) << 16);
        wa1.z = f2bf(av3.x) | ((unsigned)f2bf(av3.y) << 16);
        wa1.w = f2bf(av3.z) | ((unsigned)f2bf(av3.w) << 16);
        uint4* adst = (uint4*)&As[srow * 32 + sh];
        adst[0] = wa0; adst[1] = wa1;
        uint4* bdst = (uint4*)&Bs[srow * 32 + sh];
        bdst[0] = bv0; bdst[1] = bv1;

        __syncthreads();

        short8 af[4], bf[4];
#pragma unroll
        for (int m = 0; m < 4; ++m)
            af[m] = *(const short8*)&As[(wm * 64 + m * 16 + l15) * 32 + l4 * 8];
#pragma unroll
        for (int n = 0; n < 4; ++n)
            bf[n] = *(const short8*)&Bs[(wn * 64 + n * 16 + l15) * 32 + l4 * 8];
#pragma unroll
        for (int m = 0; m < 4; ++m)
#pragma unroll
            for (int n = 0; n < 4; ++n)
                acc[m][n] = __builtin_amdgcn_mfma_f32_16x16x32_bf16(af[m], bf[n], acc[m][n], 0, 0, 0);
    }

    // C/D layout: col = lane&15, row = (lane>>4)*4 + reg   [m89-verified]
#pragma unroll
    for (int m = 0; m < 4; ++m) {
        int rbase = row0 + wm * 64 + m * 16 + l4 * 4;
#pragma unroll
        for (int n = 0; n < 4; ++n) {
            int col = col0 + wn * 64 + n * 16 + l15;
#pragma unroll
            for (int r = 0; r < 4; ++r)
                C[(size_t)(rbase + r) * ldc + col] = acc[m][n][r];
        }
    }
}

// ---------------- launch ----------------

extern "C" void kernel_launch(void* const* d_in, const int* in_sizes, int n_in,
                              void* d_out, int out_size, void* d_ws, size_t ws_size,
                              hipStream_t stream) {
    const float* u      = (const float*)d_in[0];
    const float* logLr  = (const float*)d_in[1];
    const float* Li     = (const float*)d_in[2];
    const float* Br     = (const float*)d_in[3];
    const float* Bi     = (const float*)d_in[4];
    const float* Cr     = (const float*)d_in[5];
    const float* Ci     = (const float*)d_in[6];
    const float* D      = (const float*)d_in[7];
    const float* logDel = (const float*)d_in[8];
    float* out = (float*)d_out;

    const size_t M = (size_t)BATCH * SEQ;  // 32768
    float* ws    = (float*)d_ws;
    float* V     = ws;                     // M*128 = 4,194,304 floats
    float* E     = V + M * 128;            // 65536
    float* Carry = E + 65536;              // 65536
    float* ApR   = Carry + 65536;          // 65*64 = 4160
    float* ApI   = ApR + 4160;             // 4160
    float* sr    = ApI + 4160;             // 64
    float* si    = sr + 64;                // 64
    unsigned short* Mv = (unsigned short*)(si + 64);  // 128*512 bf16
    unsigned short* W  = Mv + 128 * 512;              // 512*640 bf16

    hipLaunchKernelGGL(k_consts, dim3(1), dim3(64), 0, stream,
                       logLr, Li, logDel, sr, si, ApR, ApI);
    hipLaunchKernelGGL(k_build_Mv, dim3(128), dim3(512), 0, stream, Br, Bi, sr, si, Mv);
    hipLaunchKernelGGL(k_build_W, dim3(512), dim3(640), 0, stream, Cr, Ci, D, W);

    // GEMM1: V (M x 128) = U (M x 512, fp32) * Mv^T (bf16)
    hipLaunchKernelGGL((mfma_gemm<0>), dim3(M / 128, 1), dim3(256), 0, stream,
                       (const float*)nullptr, 0, u, DMODEL, Mv, DMODEL, V, 128, DMODEL);

    // scan (fp32, in place in V)
    hipLaunchKernelGGL(k_scanA, dim3(BATCH * (NCHUNK / 4)), dim3(256), 0, stream, V, ApR, ApI, E);
    hipLaunchKernelGGL(k_scanB, dim3(BATCH), dim3(64), 0, stream, E, Carry, ApR, ApI);
    hipLaunchKernelGGL(k_scanC, dim3(BATCH * (NCHUNK / 4)), dim3(256), 0, stream, V, Carry, ApR, ApI);

    // GEMM23 fused: out (M x 512) = [X | U] (M x 640) * [2Cr | -2Ci | D]^T, split at k=128
    hipLaunchKernelGGL((mfma_gemm<128>), dim3(M / 128, DMODEL / 128), dim3(256), 0, stream,
                       V, 128, u, DMODEL, W, 640, out, DMODEL, 640);
}

// Round 3
// 104.278 us; speedup vs baseline: 3.3998x; 1.0206x over previous
//
#include <hip/hip_runtime.h>
#include <hip/hip_bf16.h>
#include <stdint.h>

// S5 layer on MI355X — round 3: pure-bf16 m97-structure GEMMs with global_load_lds.
//   GEMM1 : V = U(fp32) @ Mv^T   (A reg-staged+cvt, B via global_load_lds; side-writes Ub bf16)
//   scan  : x[t] = A x[t-1] + v[t]  fp32 in V; scanC emits Xb bf16
//   GEMM23: out = [Xb | Ub] @ [2Cr | -2Ci | D]^T  (all global_load_lds, K=640)

#define BATCH 8
#define SEQ   4096
#define DMODEL 512
#define HALF  64
#define CHUNK 64
#define NCHUNK (SEQ / CHUNK)   // 64

typedef __attribute__((ext_vector_type(8))) short short8;
typedef __attribute__((ext_vector_type(4))) float f32x4;

__device__ __forceinline__ unsigned short f2bf(float f) {
    unsigned int u = __float_as_uint(f);
    u += 0x7fffu + ((u >> 16) & 1u);
    return (unsigned short)(u >> 16);
}

#define GLOAD_LDS16(g, l)                                                    \
    __builtin_amdgcn_global_load_lds(                                        \
        (const __attribute__((address_space(1))) unsigned int*)(g),          \
        (__attribute__((address_space(3))) unsigned int*)(l), 16, 0, 0)

// ---------------- precompute ----------------

__global__ void k_consts(const float* __restrict__ logLr,
                         const float* __restrict__ Li_in,
                         const float* __restrict__ logDelta,
                         float* __restrict__ sr, float* __restrict__ si,
                         float* __restrict__ ApR, float* __restrict__ ApI) {
    int n = threadIdx.x;  // 0..63
    float Delta = expf(logDelta[0]);
    float llr = fminf(fmaxf(logLr[n], -10.f), 10.f);
    float Lr = -expf(llr);
    float Li = Li_in[n];
    float dr = 1.f - 0.5f * Delta * Lr;
    float di = -0.5f * Delta * Li;
    float dn = dr * dr + di * di;
    float nr = 1.f + 0.5f * Delta * Lr;
    float ni = 0.5f * Delta * Li;
    float Ar = (nr * dr + ni * di) / dn;
    float Ai = (ni * dr - nr * di) / dn;
    sr[n] = Delta * dr / dn;
    si[n] = -Delta * di / dn;
    float pr = 1.f, pi = 0.f;
    for (int k = 0; k <= CHUNK; ++k) {
        ApR[k * HALF + n] = pr;
        ApI[k * HALF + n] = pi;
        float npr = pr * Ar - pi * Ai;
        float npi = pr * Ai + pi * Ar;
        pr = npr; pi = npi;
    }
}

__global__ void k_build_Mv(const float* __restrict__ Br, const float* __restrict__ Bi,
                           const float* __restrict__ sr, const float* __restrict__ si,
                           unsigned short* __restrict__ Mv) {
    int np = blockIdx.x, p = threadIdx.x;
    int n = np & 63;
    float br = Br[n * DMODEL + p], bi = Bi[n * DMODEL + p];
    float v = (np < HALF) ? (sr[n] * br - si[n] * bi)
                          : (si[n] * br + sr[n] * bi);
    Mv[np * DMODEL + p] = f2bf(v);
}

__global__ void k_build_W(const float* __restrict__ Cr, const float* __restrict__ Ci,
                          const float* __restrict__ D, unsigned short* __restrict__ W) {
    int p = blockIdx.x, j = threadIdx.x;
    float v;
    if (j < HALF) v = 2.f * Cr[p * HALF + j];
    else if (j < 2 * HALF) v = -2.f * Ci[p * HALF + (j - HALF)];
    else v = D[p * DMODEL + (j - 2 * HALF)];
    W[p * 640 + j] = f2bf(v);
}

// ---------------- scan (fp32 in V) ----------------

__global__ void k_scanA(float* __restrict__ V,
                        const float* __restrict__ ApR, const float* __restrict__ ApI,
                        float* __restrict__ E) {
    int tid = threadIdx.x;
    int n = tid & 63;
    int cc = tid >> 6;
    int b = blockIdx.x >> 4;
    int c = ((blockIdx.x & 15) << 2) + cc;
    float Ar = ApR[HALF + n], Ai = ApI[HALF + n];
    float xr = 0.f, xi = 0.f;
    size_t base = ((size_t)b * SEQ + (size_t)c * CHUNK) * 128 + n;
    for (int tl = 0; tl < CHUNK; ++tl) {
        float vr = V[base], vi = V[base + 64];
        float nxr = Ar * xr - Ai * xi + vr;
        float nxi = Ar * xi + Ai * xr + vi;
        xr = nxr; xi = nxi;
        V[base] = xr; V[base + 64] = xi;
        base += 128;
    }
    int eidx = ((b * NCHUNK + c) * 2) * HALF + n;
    E[eidx] = xr; E[eidx + 64] = xi;
}

__global__ void k_scanB(const float* __restrict__ E, float* __restrict__ Carry,
                        const float* __restrict__ ApR, const float* __restrict__ ApI) {
    int n = threadIdx.x;
    int b = blockIdx.x;
    float ALr = ApR[CHUNK * HALF + n], ALi = ApI[CHUNK * HALF + n];
    float Gr = 0.f, Gi = 0.f;
    for (int c = 0; c < NCHUNK; ++c) {
        int idx = ((b * NCHUNK + c) * 2) * HALF + n;
        Carry[idx] = Gr; Carry[idx + 64] = Gi;
        float er = E[idx], ei = E[idx + 64];
        float ngr = ALr * Gr - ALi * Gi + er;
        float ngi = ALr * Gi + ALi * Gr + ei;
        Gr = ngr; Gi = ngi;
    }
}

// Phase C: x = local + A^(tl+1)*carry; write bf16 Xb (and optionally fp32 V for fallback path)
template <int WRITE_V, int WRITE_XB>
__global__ void k_scanC(float* __restrict__ V, const float* __restrict__ Carry,
                        const float* __restrict__ ApR, const float* __restrict__ ApI,
                        unsigned short* __restrict__ Xb) {
    int tid = threadIdx.x;
    int n = tid & 63;
    int cc = tid >> 6;
    int b = blockIdx.x >> 4;
    int c = ((blockIdx.x & 15) << 2) + cc;
    int cidx = ((b * NCHUNK + c) * 2) * HALF + n;
    float cr = (c == 0) ? 0.f : Carry[cidx];
    float ci = (c == 0) ? 0.f : Carry[cidx + 64];
    size_t base = ((size_t)b * SEQ + (size_t)c * CHUNK) * 128 + n;
    for (int tl = 0; tl < CHUNK; ++tl) {
        float pr = ApR[(tl + 1) * HALF + n], pi = ApI[(tl + 1) * HALF + n];
        float xr = V[base]      + pr * cr - pi * ci;
        float xi = V[base + 64] + pr * ci + pi * cr;
        if (WRITE_V) { V[base] = xr; V[base + 64] = xi; }
        if (WRITE_XB) { Xb[base] = f2bf(xr); Xb[base + 64] = f2bf(xi); }
        base += 128;
    }
}

// ---------------- GEMM1: V = U(fp32, reg-staged) @ Mv^T(bf16, gload_lds) ----------------
// 128x128 tile (N=128 exactly), BK=32, 256 thr = 4 waves 2x2, 16x16x32 MFMA.
__global__ __launch_bounds__(256) void gemm1(const float* __restrict__ U,
                                             const unsigned short* __restrict__ Mv,
                                             float* __restrict__ V,
                                             unsigned short* __restrict__ Ub,
                                             int writeUb) {
    __shared__ __align__(16) unsigned short As[128 * 32];
    __shared__ __align__(16) unsigned short Bs[128 * 32];
    const int tid = threadIdx.x;
    const int lane = tid & 63;
    const int w = tid >> 6;
    const int wm = w >> 1, wn = w & 1;
    const int l15 = lane & 15, l4 = lane >> 4;
    const int row0 = blockIdx.x * 128;
    const int srow = tid >> 1;
    const int sh = (tid & 1) << 4;

    f32x4 acc[4][4];
#pragma unroll
    for (int m = 0; m < 4; ++m)
#pragma unroll
        for (int n = 0; n < 4; ++n) acc[m][n] = (f32x4)(0.f);

    for (int k0 = 0; k0 < DMODEL; k0 += 32) {
        const float* ag = U + (size_t)(row0 + srow) * DMODEL + k0 + sh;
        float4 av0 = ((const float4*)ag)[0];
        float4 av1 = ((const float4*)ag)[1];
        float4 av2 = ((const float4*)ag)[2];
        float4 av3 = ((const float4*)ag)[3];

        __syncthreads();   // prior tile's LDS reads complete

        // B tile via global_load_lds (wave-uniform LDS base + lane*16)
#pragma unroll
        for (int i = 0; i < 2; ++i) {
            int c = i * 256 + w * 64 + lane;
            GLOAD_LDS16(Mv + (size_t)(c >> 2) * DMODEL + k0 + (c & 3) * 8,
                        &Bs[(i * 256 + w * 64) * 8]);
        }

        uint4 wa0, wa1;
        wa0.x = f2bf(av0.x) | ((unsigned)f2bf(av0.y) << 16);
        wa0.y = f2bf(av0.z) | ((unsigned)f2bf(av0.w) << 16);
        wa0.z = f2bf(av1.x) | ((unsigned)f2bf(av1.y) << 16);
        wa0.w = f2bf(av1.z) | ((unsigned)f2bf(av1.w) << 16);
        wa1.x = f2bf(av2.x) | ((unsigned)f2bf(av2.y) << 16);
        wa1.y = f2bf(av2.z) | ((unsigned)f2bf(av2.w) << 16);
        wa1.z = f2bf(av3.x) | ((unsigned)f2bf(av3.y) << 16);
        wa1.w = f2bf(av3.z) | ((unsigned)f2bf(av3.w) << 16);
        uint4* adst = (uint4*)&As[srow * 32 + sh];
        adst[0] = wa0; adst[1] = wa1;
        if (writeUb) {
            uint4* ud = (uint4*)&Ub[(size_t)(row0 + srow) * DMODEL + k0 + sh];
            ud[0] = wa0; ud[1] = wa1;
        }

        __syncthreads();   // vmcnt(0): B staged; lgkm: As written

        short8 af[4], bf[4];
#pragma unroll
        for (int m = 0; m < 4; ++m)
            af[m] = *(const short8*)&As[(wm * 64 + m * 16 + l15) * 32 + l4 * 8];
#pragma unroll
        for (int n = 0; n < 4; ++n)
            bf[n] = *(const short8*)&Bs[(wn * 64 + n * 16 + l15) * 32 + l4 * 8];
#pragma unroll
        for (int m = 0; m < 4; ++m)
#pragma unroll
            for (int n = 0; n < 4; ++n)
                acc[m][n] = __builtin_amdgcn_mfma_f32_16x16x32_bf16(af[m], bf[n], acc[m][n], 0, 0, 0);
    }

#pragma unroll
    for (int m = 0; m < 4; ++m) {
        int rbase = row0 + wm * 64 + m * 16 + l4 * 4;
#pragma unroll
        for (int n = 0; n < 4; ++n) {
            int col = wn * 64 + n * 16 + l15;
#pragma unroll
            for (int r = 0; r < 4; ++r)
                V[(size_t)(rbase + r) * 128 + col] = acc[m][n][r];
        }
    }
}

// ---------------- GEMM23: out = [Xb | Ub] @ W^T, all bf16 via global_load_lds ----------------
__global__ __launch_bounds__(256) void gemm23(const unsigned short* __restrict__ Xb,
                                              const unsigned short* __restrict__ Ub,
                                              const unsigned short* __restrict__ W,
                                              float* __restrict__ C) {
    __shared__ __align__(16) unsigned short As[128 * 32];
    __shared__ __align__(16) unsigned short Bs[128 * 32];
    const int tid = threadIdx.x;
    const int lane = tid & 63;
    const int w = tid >> 6;
    const int wm = w >> 1, wn = w & 1;
    const int l15 = lane & 15, l4 = lane >> 4;
    const int row0 = blockIdx.x * 128;
    const int col0 = blockIdx.y * 128;

    f32x4 acc[4][4];
#pragma unroll
    for (int m = 0; m < 4; ++m)
#pragma unroll
        for (int n = 0; n < 4; ++n) acc[m][n] = (f32x4)(0.f);

    for (int k0 = 0; k0 < 640; k0 += 32) {
        const unsigned short* ap;
        int lda, kk;
        if (k0 < 128) { ap = Xb; lda = 128; kk = k0; }
        else          { ap = Ub; lda = DMODEL; kk = k0 - 128; }

        __syncthreads();   // prior tile's LDS reads complete

#pragma unroll
        for (int i = 0; i < 2; ++i) {
            int c = i * 256 + w * 64 + lane;
            GLOAD_LDS16(ap + (size_t)(row0 + (c >> 2)) * lda + kk + (c & 3) * 8,
                        &As[(i * 256 + w * 64) * 8]);
            GLOAD_LDS16(W + (size_t)(col0 + (c >> 2)) * 640 + k0 + (c & 3) * 8,
                        &Bs[(i * 256 + w * 64) * 8]);
        }

        __syncthreads();   // vmcnt(0) drain: tiles staged

        short8 af[4], bf[4];
#pragma unroll
        for (int m = 0; m < 4; ++m)
            af[m] = *(const short8*)&As[(wm * 64 + m * 16 + l15) * 32 + l4 * 8];
#pragma unroll
        for (int n = 0; n < 4; ++n)
            bf[n] = *(const short8*)&Bs[(wn * 64 + n * 16 + l15) * 32 + l4 * 8];
#pragma unroll
        for (int m = 0; m < 4; ++m)
#pragma unroll
            for (int n = 0; n < 4; ++n)
                acc[m][n] = __builtin_amdgcn_mfma_f32_16x16x32_bf16(af[m], bf[n], acc[m][n], 0, 0, 0);
    }

#pragma unroll
    for (int m = 0; m < 4; ++m) {
        int rbase = row0 + wm * 64 + m * 16 + l4 * 4;
#pragma unroll
        for (int n = 0; n < 4; ++n) {
            int col = col0 + wn * 64 + n * 16 + l15;
#pragma unroll
            for (int r = 0; r < 4; ++r)
                C[(size_t)(rbase + r) * DMODEL + col] = acc[m][n][r];
        }
    }
}

// ---------------- fallback GEMM23 (fp32 A reg-staged) for small ws ----------------
__global__ __launch_bounds__(256) void gemm23_f32a(
    const float* __restrict__ A0, int lda0,
    const float* __restrict__ A1, int lda1,
    const unsigned short* __restrict__ B, int ldb,
    float* __restrict__ C, int ldc, int K, int SPLIT)
{
    __shared__ __align__(16) unsigned short As[128 * 32];
    __shared__ __align__(16) unsigned short Bs[128 * 32];
    const int tid = threadIdx.x;
    const int lane = tid & 63;
    const int w = tid >> 6;
    const int wm = w >> 1, wn = w & 1;
    const int l15 = lane & 15, l4 = lane >> 4;
    const int row0 = blockIdx.x * 128;
    const int col0 = blockIdx.y * 128;
    const int srow = tid >> 1;
    const int sh = (tid & 1) << 4;

    f32x4 acc[4][4];
#pragma unroll
    for (int m = 0; m < 4; ++m)
#pragma unroll
        for (int n = 0; n < 4; ++n) acc[m][n] = (f32x4)(0.f);

    for (int k0 = 0; k0 < K; k0 += 32) {
        const float* ap; int lda, kk;
        if (k0 < SPLIT) { ap = A0; lda = lda0; kk = k0; }
        else { ap = A1; lda = lda1; kk = k0 - SPLIT; }
        const float* ag = ap + (size_t)(row0 + srow) * lda + kk + sh;
        float4 av0 = ((const float4*)ag)[0];
        float4 av1 = ((const float4*)ag)[1];
        float4 av2 = ((const float4*)ag)[2];
        float4 av3 = ((const float4*)ag)[3];

        __syncthreads();

#pragma unroll
        for (int i = 0; i < 2; ++i) {
            int c = i * 256 + w * 64 + lane;
            GLOAD_LDS16(B + (size_t)(col0 + (c >> 2)) * ldb + k0 + (c & 3) * 8,
                        &Bs[(i * 256 + w * 64) * 8]);
        }

        uint4 wa0, wa1;
        wa0.x = f2bf(av0.x) | ((unsigned)f2bf(av0.y) << 16);
        wa0.y = f2bf(av0.z) | ((unsigned)f2bf(av0.w) << 16);
        wa0.z = f2bf(av1.x) | ((unsigned)f2bf(av1.y) << 16);
        wa0.w = f2bf(av1.z) | ((unsigned)f2bf(av1.w) << 16);
        wa1.x = f2bf(av2.x) | ((unsigned)f2bf(av2.y) << 16);
        wa1.y = f2bf(av2.z) | ((unsigned)f2bf(av2.w) << 16);
        wa1.z = f2bf(av3.x) | ((unsigned)f2bf(av3.y) << 16);
        wa1.w = f2bf(av3.z) | ((unsigned)f2bf(av3.w) << 16);
        uint4* adst = (uint4*)&As[srow * 32 + sh];
        adst[0] = wa0; adst[1] = wa1;

        __syncthreads();

        short8 af[4], bf[4];
#pragma unroll
        for (int m = 0; m < 4; ++m)
            af[m] = *(const short8*)&As[(wm * 64 + m * 16 + l15) * 32 + l4 * 8];
#pragma unroll
        for (int n = 0; n < 4; ++n)
            bf[n] = *(const short8*)&Bs[(wn * 64 + n * 16 + l15) * 32 + l4 * 8];
#pragma unroll
        for (int m = 0; m < 4; ++m)
#pragma unroll
            for (int n = 0; n < 4; ++n)
                acc[m][n] = __builtin_amdgcn_mfma_f32_16x16x32_bf16(af[m], bf[n], acc[m][n], 0, 0, 0);
    }

#pragma unroll
    for (int m = 0; m < 4; ++m) {
        int rbase = row0 + wm * 64 + m * 16 + l4 * 4;
#pragma unroll
        for (int n = 0; n < 4; ++n) {
            int col = col0 + wn * 64 + n * 16 + l15;
#pragma unroll
            for (int r = 0; r < 4; ++r)
                C[(size_t)(rbase + r) * ldc + col] = acc[m][n][r];
        }
    }
}

// ---------------- launch ----------------

extern "C" void kernel_launch(void* const* d_in, const int* in_sizes, int n_in,
                              void* d_out, int out_size, void* d_ws, size_t ws_size,
                              hipStream_t stream) {
    const float* u      = (const float*)d_in[0];
    const float* logLr  = (const float*)d_in[1];
    const float* Li     = (const float*)d_in[2];
    const float* Br     = (const float*)d_in[3];
    const float* Bi     = (const float*)d_in[4];
    const float* Cr     = (const float*)d_in[5];
    const float* Ci     = (const float*)d_in[6];
    const float* D      = (const float*)d_in[7];
    const float* logDel = (const float*)d_in[8];
    float* out = (float*)d_out;

    const size_t M = (size_t)BATCH * SEQ;  // 32768
    float* ws    = (float*)d_ws;
    float* V     = ws;                     // M*128 floats
    float* E     = V + M * 128;            // 65536
    float* Carry = E + 65536;              // 65536
    float* ApR   = Carry + 65536;          // 4160
    float* ApI   = ApR + 4160;             // 4160
    float* sr    = ApI + 4160;             // 64
    float* si    = sr + 64;                // 64
    unsigned short* Mv = (unsigned short*)(si + 64);  // 128*512
    unsigned short* W  = Mv + 128 * 512;              // 512*640
    unsigned short* Ub = W + 512 * 640;               // M*512
    unsigned short* Xb = Ub + M * 512;                // M*128
    const size_t need = (size_t)((float*)(Xb + M * 128) - ws) * 4;
    const int big = (ws_size >= need);

    hipLaunchKernelGGL(k_consts, dim3(1), dim3(64), 0, stream,
                       logLr, Li, logDel, sr, si, ApR, ApI);
    hipLaunchKernelGGL(k_build_Mv, dim3(128), dim3(512), 0, stream, Br, Bi, sr, si, Mv);
    hipLaunchKernelGGL(k_build_W, dim3(512), dim3(640), 0, stream, Cr, Ci, D, W);

    // GEMM1: V = U @ Mv^T (+ Ub side-write in big path)
    hipLaunchKernelGGL(gemm1, dim3(M / 128), dim3(256), 0, stream, u, Mv, V, Ub, big);

    // scan
    hipLaunchKernelGGL(k_scanA, dim3(BATCH * (NCHUNK / 4)), dim3(256), 0, stream, V, ApR, ApI, E);
    hipLaunchKernelGGL(k_scanB, dim3(BATCH), dim3(64), 0, stream, E, Carry, ApR, ApI);
    if (big) {
        hipLaunchKernelGGL((k_scanC<0, 1>), dim3(BATCH * (NCHUNK / 4)), dim3(256), 0, stream,
                           V, Carry, ApR, ApI, Xb);
        hipLaunchKernelGGL(gemm23, dim3(M / 128, DMODEL / 128), dim3(256), 0, stream,
                           Xb, Ub, W, out);
    } else {
        hipLaunchKernelGGL((k_scanC<1, 0>), dim3(BATCH * (NCHUNK / 4)), dim3(256), 0, stream,
                           V, Carry, ApR, ApI, (unsigned short*)nullptr);
        hipLaunchKernelGGL(gemm23_f32a, dim3(M / 128, DMODEL / 128), dim3(256), 0, stream,
                           V, 128, u, DMODEL, W, 640, out, DMODEL, 640, 128);
    }
}

// Round 5
// 100.155 us; speedup vs baseline: 3.5397x; 1.0412x over previous
//
#include <hip/hip_runtime.h>
#include <hip/hip_bf16.h>
#include <stdint.h>

// S5 layer on MI355X — round 5: exact log-depth carry scan (fix round-4's
// invalid windowed approximation: high-freq poles have |A^64| ~ 0.94, window
// truncation error ~0.4 -> absmax 6.6. Hillis-Steele shuffle scan is exact).
//   GEMM1 : V = U(fp32) @ Mv^T  (A reg-staged+cvt, B gload_lds; side-writes Ub bf16)
//   scanA : chunk-end local states E (V read-only)
//   scanB : per-(b,n) inclusive prefix over 64 chunks via __shfl_up, exclusive carry out
//   scanC : recurrence re-run seeded with exact carry; emits Xb bf16
//   GEMM23: out = [Xb | Ub] @ [2Cr | -2Ci | D]^T  (all gload_lds, K=640)

#define BATCH 8
#define SEQ   4096
#define DMODEL 512
#define HALF  64
#define CHUNK 64
#define NCHUNK (SEQ / CHUNK)   // 64

typedef __attribute__((ext_vector_type(8))) short short8;
typedef __attribute__((ext_vector_type(4))) float f32x4;

__device__ __forceinline__ unsigned short f2bf(float f) {
    unsigned int u = __float_as_uint(f);
    u += 0x7fffu + ((u >> 16) & 1u);
    return (unsigned short)(u >> 16);
}

#define GLOAD_LDS16(g, l)                                                    \
    __builtin_amdgcn_global_load_lds(                                        \
        (const __attribute__((address_space(1))) unsigned int*)(g),          \
        (__attribute__((address_space(3))) unsigned int*)(l), 16, 0, 0)

// ---------------- precompute ----------------

__global__ void k_consts(const float* __restrict__ logLr,
                         const float* __restrict__ Li_in,
                         const float* __restrict__ logDelta,
                         float* __restrict__ sr, float* __restrict__ si,
                         float* __restrict__ ApR, float* __restrict__ ApI) {
    int n = threadIdx.x;  // 0..63
    float Delta = expf(logDelta[0]);
    float llr = fminf(fmaxf(logLr[n], -10.f), 10.f);
    float Lr = -expf(llr);
    float Li = Li_in[n];
    float dr = 1.f - 0.5f * Delta * Lr;
    float di = -0.5f * Delta * Li;
    float dn = dr * dr + di * di;
    float nr = 1.f + 0.5f * Delta * Lr;
    float ni = 0.5f * Delta * Li;
    float Ar = (nr * dr + ni * di) / dn;
    float Ai = (ni * dr - nr * di) / dn;
    sr[n] = Delta * dr / dn;
    si[n] = -Delta * di / dn;
    float pr = 1.f, pi = 0.f;
    for (int k = 0; k <= CHUNK; ++k) {
        ApR[k * HALF + n] = pr;
        ApI[k * HALF + n] = pi;
        float npr = pr * Ar - pi * Ai;
        float npi = pr * Ai + pi * Ar;
        pr = npr; pi = npi;
    }
}

__global__ void k_build_Mv(const float* __restrict__ Br, const float* __restrict__ Bi,
                           const float* __restrict__ sr, const float* __restrict__ si,
                           unsigned short* __restrict__ Mv) {
    int np = blockIdx.x, p = threadIdx.x;
    int n = np & 63;
    float br = Br[n * DMODEL + p], bi = Bi[n * DMODEL + p];
    float v = (np < HALF) ? (sr[n] * br - si[n] * bi)
                          : (si[n] * br + sr[n] * bi);
    Mv[np * DMODEL + p] = f2bf(v);
}

__global__ void k_build_W(const float* __restrict__ Cr, const float* __restrict__ Ci,
                          const float* __restrict__ D, unsigned short* __restrict__ W) {
    int p = blockIdx.x, j = threadIdx.x;
    float v;
    if (j < HALF) v = 2.f * Cr[p * HALF + j];
    else if (j < 2 * HALF) v = -2.f * Ci[p * HALF + (j - HALF)];
    else v = D[p * DMODEL + (j - 2 * HALF)];
    W[p * 640 + j] = f2bf(v);
}

// ---------------- scan ----------------
// scanA: grid 256 x 128 threads; thread = (b, c, n); V read-only, writes E.

__global__ void k_scanA(const float* __restrict__ V,
                        const float* __restrict__ ApR, const float* __restrict__ ApI,
                        float* __restrict__ E) {
    int tid = threadIdx.x;
    int n = tid & 63;
    int c = ((blockIdx.x & 31) << 1) + (tid >> 6);
    int b = blockIdx.x >> 5;
    float Ar = ApR[HALF + n], Ai = ApI[HALF + n];
    float xr = 0.f, xi = 0.f;
    size_t base = ((size_t)b * SEQ + (size_t)c * CHUNK) * 128 + n;
    for (int tl = 0; tl < CHUNK; ++tl) {
        float vr = V[base], vi = V[base + 64];
        float nxr = Ar * xr - Ai * xi + vr;
        float nxi = Ar * xi + Ai * xr + vi;
        xr = nxr; xi = nxi;
        base += 128;
    }
    int eidx = ((b * NCHUNK + c) * 2) * HALF + n;
    E[eidx] = xr; E[eidx + 64] = xi;
}

// scanB: exact exclusive carry prefix via Hillis-Steele over the 64 chunks.
// grid 8 (batch) x 512 threads (8 waves); wave w handles poles n = w, w+8, ...
// lane = chunk index c. S_c = sum_{j<=c} (A^64)^(c-j) E_j; Carry_c = S_{c-1}.
__global__ void k_scanB(const float* __restrict__ E, float* __restrict__ Carry,
                        const float* __restrict__ ApR, const float* __restrict__ ApI) {
    int lane = threadIdx.x & 63;   // chunk c
    int wv = threadIdx.x >> 6;     // 0..7
    int b = blockIdx.x;
    for (int n = wv; n < HALF; n += 8) {
        float wr = ApR[CHUNK * HALF + n], wi = ApI[CHUNK * HALF + n];  // A^64
        int idx = ((b * NCHUNK + lane) * 2) * HALF + n;
        float sR = E[idx], sI = E[idx + 64];
#pragma unroll
        for (int s = 1; s < 64; s <<= 1) {
            float pR = __shfl_up(sR, s, 64);
            float pI = __shfl_up(sI, s, 64);
            if (lane >= s) {
                sR += wr * pR - wi * pI;
                sI += wr * pI + wi * pR;
            }
            float nwr = wr * wr - wi * wi;   // w <- w^2 (uniform per wave-n)
            float nwi = 2.f * wr * wi;
            wr = nwr; wi = nwi;
        }
        float cR = __shfl_up(sR, 1, 64);
        float cI = __shfl_up(sI, 1, 64);
        if (lane == 0) { cR = 0.f; cI = 0.f; }
        Carry[idx] = cR; Carry[idx + 64] = cI;
    }
}

// scanC: recurrence seeded with exact carry; emits Xb (and/or V for fallback).
template <int WRITE_V, int WRITE_XB>
__global__ void k_scanC(float* __restrict__ V, const float* __restrict__ Carry,
                        const float* __restrict__ ApR, const float* __restrict__ ApI,
                        unsigned short* __restrict__ Xb) {
    int tid = threadIdx.x;
    int n = tid & 63;
    int c = ((blockIdx.x & 31) << 1) + (tid >> 6);
    int b = blockIdx.x >> 5;
    int cidx = ((b * NCHUNK + c) * 2) * HALF + n;
    float xr = Carry[cidx], xi = Carry[cidx + 64];
    float Ar = ApR[HALF + n], Ai = ApI[HALF + n];
    size_t base = ((size_t)b * SEQ + (size_t)c * CHUNK) * 128 + n;
    for (int tl = 0; tl < CHUNK; ++tl) {
        float vr = V[base], vi = V[base + 64];
        float nxr = Ar * xr - Ai * xi + vr;
        float nxi = Ar * xi + Ai * xr + vi;
        xr = nxr; xi = nxi;
        if (WRITE_XB) { Xb[base] = f2bf(xr); Xb[base + 64] = f2bf(xi); }
        if (WRITE_V)  { V[base] = xr; V[base + 64] = xi; }
        base += 128;
    }
}

// ---------------- GEMM1: V = U(fp32, reg-staged) @ Mv^T(bf16, gload_lds) ----------------
__global__ __launch_bounds__(256) void gemm1(const float* __restrict__ U,
                                             const unsigned short* __restrict__ Mv,
                                             float* __restrict__ V,
                                             unsigned short* __restrict__ Ub,
                                             int writeUb) {
    __shared__ __align__(16) unsigned short As[128 * 32];
    __shared__ __align__(16) unsigned short Bs[128 * 32];
    const int tid = threadIdx.x;
    const int lane = tid & 63;
    const int w = tid >> 6;
    const int wm = w >> 1, wn = w & 1;
    const int l15 = lane & 15, l4 = lane >> 4;
    const int row0 = blockIdx.x * 128;
    const int srow = tid >> 1;
    const int sh = (tid & 1) << 4;

    f32x4 acc[4][4];
#pragma unroll
    for (int m = 0; m < 4; ++m)
#pragma unroll
        for (int n = 0; n < 4; ++n) acc[m][n] = (f32x4)(0.f);

    for (int k0 = 0; k0 < DMODEL; k0 += 32) {
        const float* ag = U + (size_t)(row0 + srow) * DMODEL + k0 + sh;
        float4 av0 = ((const float4*)ag)[0];
        float4 av1 = ((const float4*)ag)[1];
        float4 av2 = ((const float4*)ag)[2];
        float4 av3 = ((const float4*)ag)[3];

        __syncthreads();

#pragma unroll
        for (int i = 0; i < 2; ++i) {
            int c = i * 256 + w * 64 + lane;
            GLOAD_LDS16(Mv + (size_t)(c >> 2) * DMODEL + k0 + (c & 3) * 8,
                        &Bs[(i * 256 + w * 64) * 8]);
        }

        uint4 wa0, wa1;
        wa0.x = f2bf(av0.x) | ((unsigned)f2bf(av0.y) << 16);
        wa0.y = f2bf(av0.z) | ((unsigned)f2bf(av0.w) << 16);
        wa0.z = f2bf(av1.x) | ((unsigned)f2bf(av1.y) << 16);
        wa0.w = f2bf(av1.z) | ((unsigned)f2bf(av1.w) << 16);
        wa1.x = f2bf(av2.x) | ((unsigned)f2bf(av2.y) << 16);
        wa1.y = f2bf(av2.z) | ((unsigned)f2bf(av2.w) << 16);
        wa1.z = f2bf(av3.x) | ((unsigned)f2bf(av3.y) << 16);
        wa1.w = f2bf(av3.z) | ((unsigned)f2bf(av3.w) << 16);
        uint4* adst = (uint4*)&As[srow * 32 + sh];
        adst[0] = wa0; adst[1] = wa1;
        if (writeUb) {
            uint4* ud = (uint4*)&Ub[(size_t)(row0 + srow) * DMODEL + k0 + sh];
            ud[0] = wa0; ud[1] = wa1;
        }

        __syncthreads();

        short8 af[4], bf[4];
#pragma unroll
        for (int m = 0; m < 4; ++m)
            af[m] = *(const short8*)&As[(wm * 64 + m * 16 + l15) * 32 + l4 * 8];
#pragma unroll
        for (int n = 0; n < 4; ++n)
            bf[n] = *(const short8*)&Bs[(wn * 64 + n * 16 + l15) * 32 + l4 * 8];
#pragma unroll
        for (int m = 0; m < 4; ++m)
#pragma unroll
            for (int n = 0; n < 4; ++n)
                acc[m][n] = __builtin_amdgcn_mfma_f32_16x16x32_bf16(af[m], bf[n], acc[m][n], 0, 0, 0);
    }

#pragma unroll
    for (int m = 0; m < 4; ++m) {
        int rbase = row0 + wm * 64 + m * 16 + l4 * 4;
#pragma unroll
        for (int n = 0; n < 4; ++n) {
            int col = wn * 64 + n * 16 + l15;
#pragma unroll
            for (int r = 0; r < 4; ++r)
                V[(size_t)(rbase + r) * 128 + col] = acc[m][n][r];
        }
    }
}

// ---------------- GEMM23: out = [Xb | Ub] @ W^T, all bf16 via gload_lds ----------------
__global__ __launch_bounds__(256) void gemm23(const unsigned short* __restrict__ Xb,
                                              const unsigned short* __restrict__ Ub,
                                              const unsigned short* __restrict__ W,
                                              float* __restrict__ C) {
    __shared__ __align__(16) unsigned short As[128 * 32];
    __shared__ __align__(16) unsigned short Bs[128 * 32];
    const int tid = threadIdx.x;
    const int lane = tid & 63;
    const int w = tid >> 6;
    const int wm = w >> 1, wn = w & 1;
    const int l15 = lane & 15, l4 = lane >> 4;
    const int row0 = blockIdx.x * 128;
    const int col0 = blockIdx.y * 128;

    f32x4 acc[4][4];
#pragma unroll
    for (int m = 0; m < 4; ++m)
#pragma unroll
        for (int n = 0; n < 4; ++n) acc[m][n] = (f32x4)(0.f);

    for (int k0 = 0; k0 < 640; k0 += 32) {
        const unsigned short* ap;
        int lda, kk;
        if (k0 < 128) { ap = Xb; lda = 128; kk = k0; }
        else          { ap = Ub; lda = DMODEL; kk = k0 - 128; }

        __syncthreads();

#pragma unroll
        for (int i = 0; i < 2; ++i) {
            int c = i * 256 + w * 64 + lane;
            GLOAD_LDS16(ap + (size_t)(row0 + (c >> 2)) * lda + kk + (c & 3) * 8,
                        &As[(i * 256 + w * 64) * 8]);
            GLOAD_LDS16(W + (size_t)(col0 + (c >> 2)) * 640 + k0 + (c & 3) * 8,
                        &Bs[(i * 256 + w * 64) * 8]);
        }

        __syncthreads();

        short8 af[4], bf[4];
#pragma unroll
        for (int m = 0; m < 4; ++m)
            af[m] = *(const short8*)&As[(wm * 64 + m * 16 + l15) * 32 + l4 * 8];
#pragma unroll
        for (int n = 0; n < 4; ++n)
            bf[n] = *(const short8*)&Bs[(wn * 64 + n * 16 + l15) * 32 + l4 * 8];
#pragma unroll
        for (int m = 0; m < 4; ++m)
#pragma unroll
            for (int n = 0; n < 4; ++n)
                acc[m][n] = __builtin_amdgcn_mfma_f32_16x16x32_bf16(af[m], bf[n], acc[m][n], 0, 0, 0);
    }

#pragma unroll
    for (int m = 0; m < 4; ++m) {
        int rbase = row0 + wm * 64 + m * 16 + l4 * 4;
#pragma unroll
        for (int n = 0; n < 4; ++n) {
            int col = col0 + wn * 64 + n * 16 + l15;
#pragma unroll
            for (int r = 0; r < 4; ++r)
                C[(size_t)(rbase + r) * DMODEL + col] = acc[m][n][r];
        }
    }
}

// ---------------- fallback GEMM23 (fp32 A reg-staged) for small ws ----------------
__global__ __launch_bounds__(256) void gemm23_f32a(
    const float* __restrict__ A0, int lda0,
    const float* __restrict__ A1, int lda1,
    const unsigned short* __restrict__ B, int ldb,
    float* __restrict__ C, int ldc, int K, int SPLIT)
{
    __shared__ __align__(16) unsigned short As[128 * 32];
    __shared__ __align__(16) unsigned short Bs[128 * 32];
    const int tid = threadIdx.x;
    const int lane = tid & 63;
    const int w = tid >> 6;
    const int wm = w >> 1, wn = w & 1;
    const int l15 = lane & 15, l4 = lane >> 4;
    const int row0 = blockIdx.x * 128;
    const int col0 = blockIdx.y * 128;
    const int srow = tid >> 1;
    const int sh = (tid & 1) << 4;

    f32x4 acc[4][4];
#pragma unroll
    for (int m = 0; m < 4; ++m)
#pragma unroll
        for (int n = 0; n < 4; ++n) acc[m][n] = (f32x4)(0.f);

    for (int k0 = 0; k0 < K; k0 += 32) {
        const float* ap; int lda, kk;
        if (k0 < SPLIT) { ap = A0; lda = lda0; kk = k0; }
        else { ap = A1; lda = lda1; kk = k0 - SPLIT; }
        const float* ag = ap + (size_t)(row0 + srow) * lda + kk + sh;
        float4 av0 = ((const float4*)ag)[0];
        float4 av1 = ((const float4*)ag)[1];
        float4 av2 = ((const float4*)ag)[2];
        float4 av3 = ((const float4*)ag)[3];

        __syncthreads();

#pragma unroll
        for (int i = 0; i < 2; ++i) {
            int c = i * 256 + w * 64 + lane;
            GLOAD_LDS16(B + (size_t)(col0 + (c >> 2)) * ldb + k0 + (c & 3) * 8,
                        &Bs[(i * 256 + w * 64) * 8]);
        }

        uint4 wa0, wa1;
        wa0.x = f2bf(av0.x) | ((unsigned)f2bf(av0.y) << 16);
        wa0.y = f2bf(av0.z) | ((unsigned)f2bf(av0.w) << 16);
        wa0.z = f2bf(av1.x) | ((unsigned)f2bf(av1.y) << 16);
        wa0.w = f2bf(av1.z) | ((unsigned)f2bf(av1.w) << 16);
        wa1.x = f2bf(av2.x) | ((unsigned)f2bf(av2.y) << 16);
        wa1.y = f2bf(av2.z) | ((unsigned)f2bf(av2.w) << 16);
        wa1.z = f2bf(av3.x) | ((unsigned)f2bf(av3.y) << 16);
        wa1.w = f2bf(av3.z) | ((unsigned)f2bf(av3.w) << 16);
        uint4* adst = (uint4*)&As[srow * 32 + sh];
        adst[0] = wa0; adst[1] = wa1;

        __syncthreads();

        short8 af[4], bf[4];
#pragma unroll
        for (int m = 0; m < 4; ++m)
            af[m] = *(const short8*)&As[(wm * 64 + m * 16 + l15) * 32 + l4 * 8];
#pragma unroll
        for (int n = 0; n < 4; ++n)
            bf[n] = *(const short8*)&Bs[(wn * 64 + n * 16 + l15) * 32 + l4 * 8];
#pragma unroll
        for (int m = 0; m < 4; ++m)
#pragma unroll
            for (int n = 0; n < 4; ++n)
                acc[m][n] = __builtin_amdgcn_mfma_f32_16x16x32_bf16(af[m], bf[n], acc[m][n], 0, 0, 0);
    }

#pragma unroll
    for (int m = 0; m < 4; ++m) {
        int rbase = row0 + wm * 64 + m * 16 + l4 * 4;
#pragma unroll
        for (int n = 0; n < 4; ++n) {
            int col = col0 + wn * 64 + n * 16 + l15;
#pragma unroll
            for (int r = 0; r < 4; ++r)
                C[(size_t)(rbase + r) * ldc + col] = acc[m][n][r];
        }
    }
}

// ---------------- launch ----------------

extern "C" void kernel_launch(void* const* d_in, const int* in_sizes, int n_in,
                              void* d_out, int out_size, void* d_ws, size_t ws_size,
                              hipStream_t stream) {
    const float* u      = (const float*)d_in[0];
    const float* logLr  = (const float*)d_in[1];
    const float* Li     = (const float*)d_in[2];
    const float* Br     = (const float*)d_in[3];
    const float* Bi     = (const float*)d_in[4];
    const float* Cr     = (const float*)d_in[5];
    const float* Ci     = (const float*)d_in[6];
    const float* D      = (const float*)d_in[7];
    const float* logDel = (const float*)d_in[8];
    float* out = (float*)d_out;

    const size_t M = (size_t)BATCH * SEQ;  // 32768
    float* ws    = (float*)d_ws;
    float* V     = ws;                     // M*128 floats
    float* E     = V + M * 128;            // 65536
    float* Carry = E + 65536;              // 65536
    float* ApR   = Carry + 65536;          // 4160
    float* ApI   = ApR + 4160;             // 4160
    float* sr    = ApI + 4160;             // 64
    float* si    = sr + 64;                // 64
    unsigned short* Mv = (unsigned short*)(si + 64);  // 128*512
    unsigned short* W  = Mv + 128 * 512;              // 512*640
    unsigned short* Ub = W + 512 * 640;               // M*512
    unsigned short* Xb = Ub + M * 512;                // M*128
    const size_t need = (size_t)((char*)(Xb + M * 128) - (char*)ws);
    const int big = (ws_size >= need);

    hipLaunchKernelGGL(k_consts, dim3(1), dim3(64), 0, stream,
                       logLr, Li, logDel, sr, si, ApR, ApI);
    hipLaunchKernelGGL(k_build_Mv, dim3(128), dim3(512), 0, stream, Br, Bi, sr, si, Mv);
    hipLaunchKernelGGL(k_build_W, dim3(512), dim3(640), 0, stream, Cr, Ci, D, W);

    // GEMM1: V = U @ Mv^T (+ Ub side-write in big path)
    hipLaunchKernelGGL(gemm1, dim3(M / 128), dim3(256), 0, stream, u, Mv, V, Ub, big);

    // scan: chunk-end states -> exact shuffle-scan carry -> seeded recurrence
    hipLaunchKernelGGL(k_scanA, dim3(256), dim3(128), 0, stream, V, ApR, ApI, E);
    hipLaunchKernelGGL(k_scanB, dim3(BATCH), dim3(512), 0, stream, E, Carry, ApR, ApI);
    if (big) {
        hipLaunchKernelGGL((k_scanC<0, 1>), dim3(256), dim3(128), 0, stream,
                           V, Carry, ApR, ApI, Xb);
        hipLaunchKernelGGL(gemm23, dim3(M / 128, DMODEL / 128), dim3(256), 0, stream,
                           Xb, Ub, W, out);
    } else {
        hipLaunchKernelGGL((k_scanC<1, 0>), dim3(256), dim3(128), 0, stream,
                           V, Carry, ApR, ApI, (unsigned short*)nullptr);
        hipLaunchKernelGGL(gemm23_f32a, dim3(M / 128, DMODEL / 128), dim3(256), 0, stream,
                           V, 128, u, DMODEL, W, 640, out, DMODEL, 640, 128);
    }
}

// Round 6
// 89.365 us; speedup vs baseline: 3.9671x; 1.1207x over previous
//
#include <hip/hip_runtime.h>
#include <hip/hip_bf16.h>
#include <stdint.h>

// S5 layer on MI355X — round 6:
//   gemm23 -> 256x256 8-wave 4-phase pipelined MFMA GEMM (T2 swizzle + T3 pipeline
//             + T5 setprio + T1 XCD swizzle), double-buffered K-tile slots.
//   gemm1  -> 64x128 tile, 8 waves, 2 blocks/CU (occupancy fix for memory-bound).
//   scan   -> unchanged exact 3-phase (shuffle-scan carry).

#define BATCH 8
#define SEQ   4096
#define DMODEL 512
#define HALF  64
#define CHUNK 64
#define NCHUNK (SEQ / CHUNK)   // 64

typedef __attribute__((ext_vector_type(8))) short short8;
typedef __attribute__((ext_vector_type(4))) float f32x4;

__device__ __forceinline__ unsigned short f2bf(float f) {
    unsigned int u = __float_as_uint(f);
    u += 0x7fffu + ((u >> 16) & 1u);
    return (unsigned short)(u >> 16);
}

#define GLOAD_LDS16(g, l)                                                    \
    __builtin_amdgcn_global_load_lds(                                        \
        (const __attribute__((address_space(1))) unsigned int*)(g),          \
        (__attribute__((address_space(3))) unsigned int*)(l), 16, 0, 0)

// ---------------- precompute ----------------

__global__ void k_consts(const float* __restrict__ logLr,
                         const float* __restrict__ Li_in,
                         const float* __restrict__ logDelta,
                         float* __restrict__ sr, float* __restrict__ si,
                         float* __restrict__ ApR, float* __restrict__ ApI) {
    int n = threadIdx.x;  // 0..63
    float Delta = expf(logDelta[0]);
    float llr = fminf(fmaxf(logLr[n], -10.f), 10.f);
    float Lr = -expf(llr);
    float Li = Li_in[n];
    float dr = 1.f - 0.5f * Delta * Lr;
    float di = -0.5f * Delta * Li;
    float dn = dr * dr + di * di;
    float nr = 1.f + 0.5f * Delta * Lr;
    float ni = 0.5f * Delta * Li;
    float Ar = (nr * dr + ni * di) / dn;
    float Ai = (ni * dr - nr * di) / dn;
    sr[n] = Delta * dr / dn;
    si[n] = -Delta * di / dn;
    float pr = 1.f, pi = 0.f;
    for (int k = 0; k <= CHUNK; ++k) {
        ApR[k * HALF + n] = pr;
        ApI[k * HALF + n] = pi;
        float npr = pr * Ar - pi * Ai;
        float npi = pr * Ai + pi * Ar;
        pr = npr; pi = npi;
    }
}

__global__ void k_build_Mv(const float* __restrict__ Br, const float* __restrict__ Bi,
                           const float* __restrict__ sr, const float* __restrict__ si,
                           unsigned short* __restrict__ Mv) {
    int np = blockIdx.x, p = threadIdx.x;
    int n = np & 63;
    float br = Br[n * DMODEL + p], bi = Bi[n * DMODEL + p];
    float v = (np < HALF) ? (sr[n] * br - si[n] * bi)
                          : (si[n] * br + sr[n] * bi);
    Mv[np * DMODEL + p] = f2bf(v);
}

__global__ void k_build_W(const float* __restrict__ Cr, const float* __restrict__ Ci,
                          const float* __restrict__ D, unsigned short* __restrict__ W) {
    int p = blockIdx.x, j = threadIdx.x;
    float v;
    if (j < HALF) v = 2.f * Cr[p * HALF + j];
    else if (j < 2 * HALF) v = -2.f * Ci[p * HALF + (j - HALF)];
    else v = D[p * DMODEL + (j - 2 * HALF)];
    W[p * 640 + j] = f2bf(v);
}

// ---------------- scan (unchanged, exact) ----------------

__global__ void k_scanA(const float* __restrict__ V,
                        const float* __restrict__ ApR, const float* __restrict__ ApI,
                        float* __restrict__ E) {
    int tid = threadIdx.x;
    int n = tid & 63;
    int c = ((blockIdx.x & 31) << 1) + (tid >> 6);
    int b = blockIdx.x >> 5;
    float Ar = ApR[HALF + n], Ai = ApI[HALF + n];
    float xr = 0.f, xi = 0.f;
    size_t base = ((size_t)b * SEQ + (size_t)c * CHUNK) * 128 + n;
    for (int tl = 0; tl < CHUNK; ++tl) {
        float vr = V[base], vi = V[base + 64];
        float nxr = Ar * xr - Ai * xi + vr;
        float nxi = Ar * xi + Ai * xr + vi;
        xr = nxr; xi = nxi;
        base += 128;
    }
    int eidx = ((b * NCHUNK + c) * 2) * HALF + n;
    E[eidx] = xr; E[eidx + 64] = xi;
}

__global__ void k_scanB(const float* __restrict__ E, float* __restrict__ Carry,
                        const float* __restrict__ ApR, const float* __restrict__ ApI) {
    int lane = threadIdx.x & 63;   // chunk c
    int wv = threadIdx.x >> 6;     // 0..7
    int b = blockIdx.x;
    for (int n = wv; n < HALF; n += 8) {
        float wr = ApR[CHUNK * HALF + n], wi = ApI[CHUNK * HALF + n];  // A^64
        int idx = ((b * NCHUNK + lane) * 2) * HALF + n;
        float sR = E[idx], sI = E[idx + 64];
#pragma unroll
        for (int s = 1; s < 64; s <<= 1) {
            float pR = __shfl_up(sR, s, 64);
            float pI = __shfl_up(sI, s, 64);
            if (lane >= s) {
                sR += wr * pR - wi * pI;
                sI += wr * pI + wi * pR;
            }
            float nwr = wr * wr - wi * wi;
            float nwi = 2.f * wr * wi;
            wr = nwr; wi = nwi;
        }
        float cR = __shfl_up(sR, 1, 64);
        float cI = __shfl_up(sI, 1, 64);
        if (lane == 0) { cR = 0.f; cI = 0.f; }
        Carry[idx] = cR; Carry[idx + 64] = cI;
    }
}

template <int WRITE_V, int WRITE_XB>
__global__ void k_scanC(float* __restrict__ V, const float* __restrict__ Carry,
                        const float* __restrict__ ApR, const float* __restrict__ ApI,
                        unsigned short* __restrict__ Xb) {
    int tid = threadIdx.x;
    int n = tid & 63;
    int c = ((blockIdx.x & 31) << 1) + (tid >> 6);
    int b = blockIdx.x >> 5;
    int cidx = ((b * NCHUNK + c) * 2) * HALF + n;
    float xr = Carry[cidx], xi = Carry[cidx + 64];
    float Ar = ApR[HALF + n], Ai = ApI[HALF + n];
    size_t base = ((size_t)b * SEQ + (size_t)c * CHUNK) * 128 + n;
    for (int tl = 0; tl < CHUNK; ++tl) {
        float vr = V[base], vi = V[base + 64];
        float nxr = Ar * xr - Ai * xi + vr;
        float nxi = Ar * xi + Ai * xr + vi;
        xr = nxr; xi = nxi;
        if (WRITE_XB) { Xb[base] = f2bf(xr); Xb[base + 64] = f2bf(xi); }
        if (WRITE_V)  { V[base] = xr; V[base + 64] = xi; }
        base += 128;
    }
}

// ---------------- GEMM1: V = U(fp32) @ Mv^T (bf16) ----------------
// 64x128 tile, 512 thr = 8 waves (2M x 4N), wave out 32x32 (acc[2][2]).
// grid M/64 = 512 blocks -> 2 blocks/CU, 4 waves/SIMD (memory-bound: TLP).
__global__ __launch_bounds__(512) void gemm1(const float* __restrict__ U,
                                             const unsigned short* __restrict__ Mv,
                                             float* __restrict__ V,
                                             unsigned short* __restrict__ Ub,
                                             int writeUb) {
    __shared__ __align__(16) unsigned short As[64 * 32];
    __shared__ __align__(16) unsigned short Bs[128 * 32];
    const int tid = threadIdx.x;
    const int lane = tid & 63;
    const int w = tid >> 6;            // 0..7
    const int wm = w >> 2, wn = w & 3; // 2 x 4
    const int l15 = lane & 15, l4 = lane >> 4;
    const int row0 = blockIdx.x * 64;
    const int srow = tid >> 3;         // 0..63
    const int sh = (tid & 7) * 4;      // 0..28

    f32x4 acc[2][2];
#pragma unroll
    for (int m = 0; m < 2; ++m)
#pragma unroll
        for (int n = 0; n < 2; ++n) acc[m][n] = (f32x4)(0.f);

    for (int k0 = 0; k0 < DMODEL; k0 += 32) {
        const float4 av = *(const float4*)(U + (size_t)(row0 + srow) * DMODEL + k0 + sh);

        __syncthreads();   // prior tile's LDS reads complete

        // B tile 128x32 bf16 = 8KB via gload_lds: chunk c = tid
        GLOAD_LDS16(Mv + (size_t)(tid >> 2) * DMODEL + k0 + (tid & 3) * 8,
                    &Bs[(w * 64) * 8]);

        uint2 wa;
        wa.x = (unsigned)f2bf(av.x) | ((unsigned)f2bf(av.y) << 16);
        wa.y = (unsigned)f2bf(av.z) | ((unsigned)f2bf(av.w) << 16);
        *(uint2*)&As[srow * 32 + sh] = wa;
        if (writeUb)
            *(uint2*)&Ub[(size_t)(row0 + srow) * DMODEL + k0 + sh] = wa;

        __syncthreads();   // vmcnt+lgkm drain: tiles staged

        short8 af[2], bf[2];
#pragma unroll
        for (int m = 0; m < 2; ++m)
            af[m] = *(const short8*)&As[(wm * 32 + m * 16 + l15) * 32 + l4 * 8];
#pragma unroll
        for (int n = 0; n < 2; ++n)
            bf[n] = *(const short8*)&Bs[(wn * 32 + n * 16 + l15) * 32 + l4 * 8];
#pragma unroll
        for (int m = 0; m < 2; ++m)
#pragma unroll
            for (int n = 0; n < 2; ++n)
                acc[m][n] = __builtin_amdgcn_mfma_f32_16x16x32_bf16(af[m], bf[n], acc[m][n], 0, 0, 0);
    }

#pragma unroll
    for (int m = 0; m < 2; ++m) {
        int rbase = row0 + wm * 32 + m * 16 + l4 * 4;
#pragma unroll
        for (int n = 0; n < 2; ++n) {
            int col = wn * 32 + n * 16 + l15;
#pragma unroll
            for (int r = 0; r < 4; ++r)
                V[(size_t)(rbase + r) * 128 + col] = acc[m][n][r];
        }
    }
}

// ---------------- GEMM23 8-wave 4-phase: out = [Xb | Ub] @ W^T ----------------
// 256x256 tile, BK=64, 512 thr = 8 waves (2M x 4N), wave out 128x64 (acc[8][4]).
// LDS: 2 K-tile slots x (A [2kc][256][32] 32KB + B same 32KB) = 128 KiB.
// Swizzle (T2): elem col ^= ((row>>3)&1)<<4 (byte bit5 ^ bit9). Linear gload_lds
// dest + inverse-swizzled per-lane global source; swizzled ds_read (rule #21).
// Pipeline (T3 minimum): stage tile t+1 (opposite slot) across tile t's 4 phases;
// one vmcnt(0)+barrier per tile (__syncthreads at boundary). Raw s_barrier inside
// phases is schedule-only; correctness rests solely on the boundary barrier.

#define STAGE_A8(t, q) do {                                                    \
    int c_ = (q) * 512 + tid;                                                  \
    int ct_ = c_ ^ (((c_ >> 5) & 1) << 1);                                     \
    int r_ = (ct_ >> 2) & 255;                                                 \
    int kcol_ = (t) * 64 + (ct_ >> 10) * 32 + (ct_ & 3) * 8;                   \
    const unsigned short* src_ = (kcol_ < 128)                                 \
        ? Xb + (size_t)(row0 + r_) * 128 + kcol_                               \
        : Ub + (size_t)(row0 + r_) * 512 + (kcol_ - 128);                      \
    GLOAD_LDS16(src_, &As[((t) & 1) * 16384 + ((q) * 512 + w * 64) * 8]);      \
} while (0)

#define STAGE_B8(t, q) do {                                                    \
    int c_ = (q) * 512 + tid;                                                  \
    int ct_ = c_ ^ (((c_ >> 5) & 1) << 1);                                     \
    int r_ = (ct_ >> 2) & 255;                                                 \
    int kcol_ = (t) * 64 + (ct_ >> 10) * 32 + (ct_ & 3) * 8;                   \
    GLOAD_LDS16(W + (size_t)(col0 + r_) * 640 + kcol_,                         \
                &Bs[((t) & 1) * 16384 + ((q) * 512 + w * 64) * 8]);            \
} while (0)

#define LDA8(t, mq) do {                                                       \
    _Pragma("unroll") for (int m2_ = 0; m2_ < 4; ++m2_)                        \
    _Pragma("unroll") for (int kh_ = 0; kh_ < 2; ++kh_) {                      \
        int r_ = wm * 128 + ((mq) * 4 + m2_) * 16 + l15;                       \
        int c_ = (l4 * 8) ^ (((r_ >> 3) & 1) << 4);                            \
        af[m2_][kh_] = *(const short8*)                                        \
            &As[((t) & 1) * 16384 + kh_ * 8192 + r_ * 32 + c_];                \
    } } while (0)

#define LDB8(t, nq) do {                                                       \
    _Pragma("unroll") for (int n2_ = 0; n2_ < 2; ++n2_)                        \
    _Pragma("unroll") for (int kh_ = 0; kh_ < 2; ++kh_) {                      \
        int r_ = wn * 64 + ((nq) * 2 + n2_) * 16 + l15;                        \
        int c_ = (l4 * 8) ^ (((r_ >> 3) & 1) << 4);                            \
        bf[n2_][kh_] = *(const short8*)                                        \
            &Bs[((t) & 1) * 16384 + kh_ * 8192 + r_ * 32 + c_];                \
    } } while (0)

#define MFMA8(mq, nq) do {                                                     \
    __builtin_amdgcn_s_setprio(1);                                             \
    _Pragma("unroll") for (int m2_ = 0; m2_ < 4; ++m2_)                        \
    _Pragma("unroll") for (int n2_ = 0; n2_ < 2; ++n2_)                        \
    _Pragma("unroll") for (int kh_ = 0; kh_ < 2; ++kh_)                        \
        acc[(mq) * 4 + m2_][(nq) * 2 + n2_] =                                  \
            __builtin_amdgcn_mfma_f32_16x16x32_bf16(                           \
                af[m2_][kh_], bf[n2_][kh_],                                    \
                acc[(mq) * 4 + m2_][(nq) * 2 + n2_], 0, 0, 0);                 \
    __builtin_amdgcn_s_setprio(0);                                             \
} while (0)

__global__ __launch_bounds__(512) void gemm23_8p(const unsigned short* __restrict__ Xb,
                                                 const unsigned short* __restrict__ Ub,
                                                 const unsigned short* __restrict__ W,
                                                 float* __restrict__ C) {
    __shared__ __align__(16) unsigned short As[2 * 16384];  // 64 KiB
    __shared__ __align__(16) unsigned short Bs[2 * 16384];  // 64 KiB
    const int tid = threadIdx.x;
    const int lane = tid & 63;
    const int w = tid >> 6;             // 0..7
    const int wm = w >> 2, wn = w & 3;  // 2 x 4
    const int l15 = lane & 15, l4 = lane >> 4;

    // T1: bijective XCD swizzle over 256 blocks (256 % 8 == 0)
    int lin = blockIdx.y * gridDim.x + blockIdx.x;  // 0..255
    int sw = (lin & 7) * 32 + (lin >> 3);
    const int row0 = (sw & 127) * 256;
    const int col0 = (sw >> 7) * 256;

    f32x4 acc[8][4];
#pragma unroll
    for (int m = 0; m < 8; ++m)
#pragma unroll
        for (int n = 0; n < 4; ++n) acc[m][n] = (f32x4)(0.f);

    // prologue: stage tile 0 fully into slot 0
#pragma unroll
    for (int q = 0; q < 4; ++q) { STAGE_A8(0, q); STAGE_B8(0, q); }
    __syncthreads();  // vmcnt(0) drain + barrier

    short8 af[4][2], bf[2][2];
    for (int t = 0; t < 10; ++t) {
        const bool pf = (t < 9);
        // phase 1: quadrant (0,0)
        LDA8(t, 0); LDB8(t, 0);
        if (pf) { STAGE_A8(t + 1, 0); STAGE_B8(t + 1, 0); }
        __builtin_amdgcn_s_barrier();
        MFMA8(0, 0);
        __builtin_amdgcn_s_barrier();
        // phase 2: (0,1)
        LDB8(t, 1);
        if (pf) { STAGE_A8(t + 1, 1); STAGE_B8(t + 1, 1); }
        __builtin_amdgcn_s_barrier();
        MFMA8(0, 1);
        __builtin_amdgcn_s_barrier();
        // phase 3: (1,0)
        LDA8(t, 1); LDB8(t, 0);
        if (pf) { STAGE_A8(t + 1, 2); STAGE_B8(t + 1, 2); }
        __builtin_amdgcn_s_barrier();
        MFMA8(1, 0);
        __builtin_amdgcn_s_barrier();
        // phase 4: (1,1)
        LDB8(t, 1);
        if (pf) { STAGE_A8(t + 1, 3); STAGE_B8(t + 1, 3); }
        __builtin_amdgcn_s_barrier();
        MFMA8(1, 1);
        __syncthreads();  // tile boundary: vmcnt(0) (t+1 staged) + all slot-t reads done
    }

#pragma unroll
    for (int m = 0; m < 8; ++m) {
        int rbase = row0 + wm * 128 + m * 16 + l4 * 4;
#pragma unroll
        for (int n = 0; n < 4; ++n) {
            int col = col0 + wn * 64 + n * 16 + l15;
#pragma unroll
            for (int r = 0; r < 4; ++r)
                C[(size_t)(rbase + r) * DMODEL + col] = acc[m][n][r];
        }
    }
}

// ---------------- fallback GEMM23 (fp32 A reg-staged, 128^2) for small ws ----------------
__global__ __launch_bounds__(256) void gemm23_f32a(
    const float* __restrict__ A0, int lda0,
    const float* __restrict__ A1, int lda1,
    const unsigned short* __restrict__ B, int ldb,
    float* __restrict__ C, int ldc, int K, int SPLIT)
{
    __shared__ __align__(16) unsigned short As[128 * 32];
    __shared__ __align__(16) unsigned short Bs[128 * 32];
    const int tid = threadIdx.x;
    const int lane = tid & 63;
    const int w = tid >> 6;
    const int wm = w >> 1, wn = w & 1;
    const int l15 = lane & 15, l4 = lane >> 4;
    const int row0 = blockIdx.x * 128;
    const int col0 = blockIdx.y * 128;
    const int srow = tid >> 1;
    const int sh = (tid & 1) << 4;

    f32x4 acc[4][4];
#pragma unroll
    for (int m = 0; m < 4; ++m)
#pragma unroll
        for (int n = 0; n < 4; ++n) acc[m][n] = (f32x4)(0.f);

    for (int k0 = 0; k0 < K; k0 += 32) {
        const float* ap; int lda, kk;
        if (k0 < SPLIT) { ap = A0; lda = lda0; kk = k0; }
        else { ap = A1; lda = lda1; kk = k0 - SPLIT; }
        const float* ag = ap + (size_t)(row0 + srow) * lda + kk + sh;
        float4 av0 = ((const float4*)ag)[0];
        float4 av1 = ((const float4*)ag)[1];
        float4 av2 = ((const float4*)ag)[2];
        float4 av3 = ((const float4*)ag)[3];

        __syncthreads();

#pragma unroll
        for (int i = 0; i < 2; ++i) {
            int c = i * 256 + w * 64 + lane;
            GLOAD_LDS16(B + (size_t)(col0 + (c >> 2)) * ldb + k0 + (c & 3) * 8,
                        &Bs[(i * 256 + w * 64) * 8]);
        }

        uint4 wa0, wa1;
        wa0.x = (unsigned)f2bf(av0.x) | ((unsigned)f2bf(av0.y) << 16);
        wa0.y = (unsigned)f2bf(av0.z) | ((unsigned)f2bf(av0.w) << 16);
        wa0.z = (unsigned)f2bf(av1.x) | ((unsigned)f2bf(av1.y) << 16);
        wa0.w = (unsigned)f2bf(av1.z) | ((unsigned)f2bf(av1.w) << 16);
        wa1.x = (unsigned)f2bf(av2.x) | ((unsigned)f2bf(av2.y) << 16);
        wa1.y = (unsigned)f2bf(av2.z) | ((unsigned)f2bf(av2.w) << 16);
        wa1.z = (unsigned)f2bf(av3.x) | ((unsigned)f2bf(av3.y) << 16);
        wa1.w = (unsigned)f2bf(av3.z) | ((unsigned)f2bf(av3.w) << 16);
        uint4* adst = (uint4*)&As[srow * 32 + sh];
        adst[0] = wa0; adst[1] = wa1;

        __syncthreads();

        short8 af[4], bf[4];
#pragma unroll
        for (int m = 0; m < 4; ++m)
            af[m] = *(const short8*)&As[(wm * 64 + m * 16 + l15) * 32 + l4 * 8];
#pragma unroll
        for (int n = 0; n < 4; ++n)
            bf[n] = *(const short8*)&Bs[(wn * 64 + n * 16 + l15) * 32 + l4 * 8];
#pragma unroll
        for (int m = 0; m < 4; ++m)
#pragma unroll
            for (int n = 0; n < 4; ++n)
                acc[m][n] = __builtin_amdgcn_mfma_f32_16x16x32_bf16(af[m], bf[n], acc[m][n], 0, 0, 0);
    }

#pragma unroll
    for (int m = 0; m < 4; ++m) {
        int rbase = row0 + wm * 64 + m * 16 + l4 * 4;
#pragma unroll
        for (int n = 0; n < 4; ++n) {
            int col = col0 + wn * 64 + n * 16 + l15;
#pragma unroll
            for (int r = 0; r < 4; ++r)
                C[(size_t)(rbase + r) * ldc + col] = acc[m][n][r];
        }
    }
}

// ---------------- launch ----------------

extern "C" void kernel_launch(void* const* d_in, const int* in_sizes, int n_in,
                              void* d_out, int out_size, void* d_ws, size_t ws_size,
                              hipStream_t stream) {
    const float* u      = (const float*)d_in[0];
    const float* logLr  = (const float*)d_in[1];
    const float* Li     = (const float*)d_in[2];
    const float* Br     = (const float*)d_in[3];
    const float* Bi     = (const float*)d_in[4];
    const float* Cr     = (const float*)d_in[5];
    const float* Ci     = (const float*)d_in[6];
    const float* D      = (const float*)d_in[7];
    const float* logDel = (const float*)d_in[8];
    float* out = (float*)d_out;

    const size_t M = (size_t)BATCH * SEQ;  // 32768
    float* ws    = (float*)d_ws;
    float* V     = ws;                     // M*128 floats
    float* E     = V + M * 128;            // 65536
    float* Carry = E + 65536;              // 65536
    float* ApR   = Carry + 65536;          // 4160
    float* ApI   = ApR + 4160;             // 4160
    float* sr    = ApI + 4160;             // 64
    float* si    = sr + 64;                // 64
    unsigned short* Mv = (unsigned short*)(si + 64);  // 128*512
    unsigned short* W  = Mv + 128 * 512;              // 512*640
    unsigned short* Ub = W + 512 * 640;               // M*512
    unsigned short* Xb = Ub + M * 512;                // M*128
    const size_t need = (size_t)((char*)(Xb + M * 128) - (char*)ws);
    const int big = (ws_size >= need);

    hipLaunchKernelGGL(k_consts, dim3(1), dim3(64), 0, stream,
                       logLr, Li, logDel, sr, si, ApR, ApI);
    hipLaunchKernelGGL(k_build_Mv, dim3(128), dim3(512), 0, stream, Br, Bi, sr, si, Mv);
    hipLaunchKernelGGL(k_build_W, dim3(512), dim3(640), 0, stream, Cr, Ci, D, W);

    // GEMM1: V = U @ Mv^T (+ Ub side-write in big path); 64-row tiles, 8 waves
    hipLaunchKernelGGL(gemm1, dim3(M / 64), dim3(512), 0, stream, u, Mv, V, Ub, big);

    // scan: chunk-end states -> exact shuffle-scan carry -> seeded recurrence
    hipLaunchKernelGGL(k_scanA, dim3(256), dim3(128), 0, stream, V, ApR, ApI, E);
    hipLaunchKernelGGL(k_scanB, dim3(BATCH), dim3(512), 0, stream, E, Carry, ApR, ApI);
    if (big) {
        hipLaunchKernelGGL((k_scanC<0, 1>), dim3(256), dim3(128), 0, stream,
                           V, Carry, ApR, ApI, Xb);
        hipLaunchKernelGGL(gemm23_8p, dim3(M / 256, DMODEL / 256), dim3(512), 0, stream,
                           Xb, Ub, W, out);
    } else {
        hipLaunchKernelGGL((k_scanC<1, 0>), dim3(256), dim3(128), 0, stream,
                           V, Carry, ApR, ApI, (unsigned short*)nullptr);
        hipLaunchKernelGGL(gemm23_f32a, dim3(M / 128, DMODEL / 128), dim3(256), 0, stream,
                           V, 128, u, DMODEL, W, 640, out, DMODEL, 640, 128);
    }
}